// Round 1
// baseline (8555.551 us; speedup 1.0000x reference)
//
#include <hip/hip_runtime.h>
#include <hip/hip_bf16.h>

#define NB   4
#define FIN  128
#define HH   256
#define WWW  256
#define LLAB 19
#define SSTY 512
#define HW   (HH*WWW)        // 65536
#define NRED (NB*HW)         // 262144 per-channel reduction count

// workspace layout (float offsets)
#define WS_NT   0            // noise transposed [B][H][W]  262144
#define WS_SUM  262144       // 128
#define WS_SSQ  262272       // 128
#define WS_MEAN 262400       // 128
#define WS_ISTD 262528       // 128
#define WS_MU   262656       // 4*19*512 = 38912
#define WS_A2   301568       // 4*19*9*256 = 175104  -> end 476672 floats (~1.9 MB)

// ---------------- noise transpose: noise[b][w][h] -> noise_t[b][h][w] --------
__global__ __launch_bounds__(256) void k_ntrans(const float* __restrict__ noise,
                                               float* __restrict__ ws) {
  __shared__ float tile[32][33];
  const int b = blockIdx.z;
  const int w0 = blockIdx.x * 32, h0 = blockIdx.y * 32;
  const int txx = threadIdx.x, tyy = threadIdx.y;
  #pragma unroll
  for (int j = 0; j < 4; ++j) {
    int wi = w0 + tyy + j * 8;
    tile[tyy + j * 8][txx] = noise[(size_t)(b * 256 + wi) * 256 + h0 + txx];
  }
  __syncthreads();
  #pragma unroll
  for (int j = 0; j < 4; ++j) {
    int hi = h0 + tyy + j * 8;
    ws[WS_NT + (size_t)(b * 256 + hi) * 256 + w0 + txx] = tile[txx][tyy + j * 8];
  }
}

// ---------------- per-channel stats over xn = x + nv[c]*noise_t --------------
__global__ __launch_bounds__(256) void k_stats(const float* __restrict__ x,
                                               const float* __restrict__ nv,
                                               float* __restrict__ ws) {
  const int bc = blockIdx.x;          // b*128 + c
  const int b = bc >> 7, c = bc & 127;
  const int t = threadIdx.x;
  const float4* xp = (const float4*)(x + (size_t)bc * HW);
  const float4* np = (const float4*)(ws + WS_NT + (size_t)b * HW);
  const float nvc = nv[c];
  float s1 = 0.f, s2 = 0.f;
  for (int i = 0; i < 64; ++i) {
    float4 xv = xp[i * 256 + t];
    float4 nz = np[i * 256 + t];
    float v0 = xv.x + nvc * nz.x; s1 += v0; s2 = fmaf(v0, v0, s2);
    float v1 = xv.y + nvc * nz.y; s1 += v1; s2 = fmaf(v1, v1, s2);
    float v2 = xv.z + nvc * nz.z; s1 += v2; s2 = fmaf(v2, v2, s2);
    float v3 = xv.w + nvc * nz.w; s1 += v3; s2 = fmaf(v3, v3, s2);
  }
  #pragma unroll
  for (int m = 32; m; m >>= 1) { s1 += __shfl_xor(s1, m); s2 += __shfl_xor(s2, m); }
  if ((t & 63) == 0) { atomicAdd(&ws[WS_SUM + c], s1); atomicAdd(&ws[WS_SSQ + c], s2); }
}

__global__ __launch_bounds__(128) void k_finalize(float* __restrict__ ws) {
  const int c = threadIdx.x;
  float mean = ws[WS_SUM + c] / (float)NRED;
  float var = ws[WS_SSQ + c] / (float)NRED - mean * mean;
  ws[WS_MEAN + c] = mean;
  ws[WS_ISTD + c] = 1.f / sqrtf(var + 1e-5f);
}

// ---------------- mu[b,j,o] = relu(sum_d style[b,j,d]*Wfc[j,o,d] + bfc[j,o]) -
__global__ __launch_bounds__(512) void k_mu(const float* __restrict__ style,
                                            const float* __restrict__ Wfc,
                                            const float* __restrict__ bfc,
                                            float* __restrict__ ws) {
  const int j = blockIdx.x, b = blockIdx.y, o = threadIdx.x;
  const float4* wrow = (const float4*)(Wfc + ((size_t)j * 512 + o) * 512);
  const float4* srow = (const float4*)(style + ((size_t)b * 19 + j) * 512);
  float acc = 0.f;
  for (int d = 0; d < 128; ++d) {
    float4 w = wrow[d];
    float4 s = srow[d];   // wave-uniform -> s_load
    acc = fmaf(w.x, s.x, acc); acc = fmaf(w.y, s.y, acc);
    acc = fmaf(w.z, s.z, acc); acc = fmaf(w.w, s.w, acc);
  }
  acc += bfc[j * 512 + o];
  ws[WS_MU + ((size_t)b * 19 + j) * 512 + o] = fmaxf(acc, 0.f);
}

// ------- A2[b][l][k][conv*128+c] = sum_s mu[b,l,s] * w_conv[c,s,k] -----------
// grid (cblk 8, ssplit 4, b 4), block 288 = (conv2 x c16 x k9)
__global__ __launch_bounds__(288) void k_atab(const float* __restrict__ w_cg,
                                              const float* __restrict__ w_cb,
                                              float* __restrict__ ws) {
  __shared__ float wlds[32 * 288];
  const int t = threadIdx.x;
  const int cblk = blockIdx.x, ssplit = blockIdx.y, b = blockIdx.z;
  const int conv = t / 144, r = t % 144, cl = r / 9, k = r % 9;
  const int c = cblk * 16 + cl;
  const float* mu = ws + WS_MU;
  float acc[19];
  #pragma unroll
  for (int l = 0; l < 19; ++l) acc[l] = 0.f;

  for (int chunk = 0; chunk < 4; ++chunk) {
    const int s0 = ssplit * 128 + chunk * 32;
    // stage 32 (conv,cl) slabs of 288 contiguous floats each (32 s x 9 k)
    for (int it = 0; it < 32; ++it) {
      int cv2 = it >> 4, cl2 = it & 15;
      const float* src = cv2 ? w_cb : w_cg;
      float v = src[((size_t)(cblk * 16 + cl2) * 512 + s0) * 9 + t];
      wlds[(t / 9) * 288 + cv2 * 144 + cl2 * 9 + (t % 9)] = v;
    }
    __syncthreads();
    for (int sl = 0; sl < 32; ++sl) {
      float w = wlds[sl * 288 + t];
      int s = s0 + sl;
      #pragma unroll
      for (int l = 0; l < 19; ++l)
        acc[l] = fmaf(mu[((size_t)b * 19 + l) * 512 + s], w, acc[l]);  // uniform -> s_load
    }
    __syncthreads();
  }
  #pragma unroll
  for (int l = 0; l < 19; ++l)
    atomicAdd(&ws[WS_A2 + (((size_t)b * 19 + l) * 9 + k) * 256 + conv * 128 + c], acc[l]);
}

// ---------------- main fused kernel ------------------------------------------
// grid (tx 16, ty 16, b*4+cg), block 512. 16x16 output tile, 32 couts/block.
__global__ __launch_bounds__(512) void k_main(
    const float* __restrict__ x, const int* __restrict__ labels,
    const float* __restrict__ w_sh, const float* __restrict__ b_sh,
    const float* __restrict__ w_g, const float* __restrict__ b_g,
    const float* __restrict__ w_b, const float* __restrict__ b_b,
    const float* __restrict__ b_cg, const float* __restrict__ b_cb,
    const float* __restrict__ noise_var,
    const float* __restrict__ g_blend, const float* __restrict__ b_blend,
    const float* __restrict__ ws, float* __restrict__ out) {
  extern __shared__ char smem[];
  int* labt = (int*)smem;                                    // 20*20 ints (l+1; 0=OOB)
  __hip_bfloat16* actv = (__hip_bfloat16*)(smem + 1600);     // [128][324]
  char* un = smem + 1600 + 128 * 324 * 2;                    // 46080-byte union
  __hip_bfloat16* wsh = (__hip_bfloat16*)un;                 // [128][20][9]
  float* alut = (float*)un;                                  // [20][9][64]
  float* bgl = (float*)(smem + 130624);
  float* bbl = bgl + 32;  float* bcgl = bgl + 64;  float* bcbl = bgl + 96;
  float* nvl = bgl + 128; float* meanl = bgl + 160; float* istdl = bgl + 192;
  float* gab = bgl + 224;

  const int t = threadIdx.x;
  const int b = blockIdx.z >> 2, cg = blockIdx.z & 3;
  const int y0 = blockIdx.y * 16, x0 = blockIdx.x * 16;
  const int c0 = cg * 32;

  if (t < 32) {
    int c = c0 + t;
    bgl[t] = b_g[c]; bbl[t] = b_b[c]; bcgl[t] = b_cg[c]; bcbl[t] = b_cb[c];
    nvl[t] = noise_var[c]; meanl[t] = ws[WS_MEAN + c]; istdl[t] = ws[WS_ISTD + c];
  }
  if (t == 0) {
    gab[0] = 1.f / (1.f + expf(-g_blend[0]));
    gab[1] = 1.f / (1.f + expf(-b_blend[0]));
  }
  // labels tile (halo 2), store l+1, 0 for OOB
  for (int idx = t; idx < 400; idx += 512) {
    int ly = idx / 20, lx = idx % 20;
    int gy = y0 - 2 + ly, gx = x0 - 2 + lx;
    int v = 0;
    if (gy >= 0 && gy < 256 && gx >= 0 && gx < 256)
      v = labels[(size_t)(b * 256 + gy) * 256 + gx] + 1;
    labt[idx] = v;
  }
  // w_sh -> LDS bf16, with zero row for l==0
  for (int idx = t; idx < 128 * 180; idx += 512) {
    int cin = idx / 180, r = idx % 180, l = r / 9, k = r % 9;
    float v = (l == 0) ? 0.f : w_sh[(size_t)(cin * 19 + (l - 1)) * 9 + k];
    wsh[idx] = __float2bfloat16(v);
  }
  __syncthreads();

  // actv tile 18x18 (halo 1), all 128 cin, bf16
  if (t < 324) {
    int py = t / 18, px = t % 18;
    int gy = y0 - 1 + py, gx = x0 - 1 + px;
    if (gy < 0 || gy >= 256 || gx < 0 || gx >= 256) {
      for (int cin = 0; cin < 128; ++cin) actv[cin * 324 + t] = __float2bfloat16(0.f);
    } else {
      int l9[9];
      #pragma unroll
      for (int dy = 0; dy < 3; ++dy)
        #pragma unroll
        for (int dx = 0; dx < 3; ++dx)
          l9[dy * 3 + dx] = labt[(py + dy) * 20 + (px + dx)];
      for (int cin = 0; cin < 128; ++cin) {
        float a = b_sh[cin];
        const __hip_bfloat16* wr = wsh + cin * 180;
        #pragma unroll
        for (int k = 0; k < 9; ++k) a += __bfloat162float(wr[l9[k] * 9 + k]);
        actv[cin * 324 + t] = __float2bfloat16(fmaxf(a, 0.f));
      }
    }
  }
  __syncthreads();

  // stage A-lut (overwrites wsh region; all wsh reads are done & synced)
  for (int idx = t; idx < 20 * 9 * 64; idx += 512) {
    int l = idx / 576, r = idx % 576, k = r / 64, cc = r % 64;
    float v = 0.f;
    if (l > 0) {
      int cv = cc >> 5, c = c0 + (cc & 31);
      v = ws[WS_A2 + (((size_t)b * 19 + (l - 1)) * 9 + k) * 256 + cv * 128 + c];
    }
    alut[(l * 9 + k) * 64 + cc] = v;
  }
  __syncthreads();

  // conv: each thread = 1 pixel x 16 couts (gamma & beta)
  const int p = t & 255;
  const int py = p >> 4, px = p & 15;
  const int ch = (__builtin_amdgcn_readfirstlane(t)) >> 8;  // wave-uniform half
  float accG[16], accB[16];
  #pragma unroll
  for (int i = 0; i < 16; ++i) { accG[i] = 0.f; accB[i] = 0.f; }

  const int cbase = c0 + ch * 16;
  for (int cin = 0; cin < 128; ++cin) {
    float in9[9];
    const __hip_bfloat16* ap = actv + cin * 324 + py * 18 + px;
    #pragma unroll
    for (int ky = 0; ky < 3; ++ky)
      #pragma unroll
      for (int kx = 0; kx < 3; ++kx)
        in9[ky * 3 + kx] = __bfloat162float(ap[ky * 18 + kx]);
    #pragma unroll
    for (int i = 0; i < 16; ++i) {
      const float* wgp = w_g + (size_t)((cbase + i) * 128 + cin) * 9;  // uniform -> s_load
      const float* wbp = w_b + (size_t)((cbase + i) * 128 + cin) * 9;
      float ag = accG[i], ab = accB[i];
      #pragma unroll
      for (int k = 0; k < 9; ++k) {
        ag = fmaf(wgp[k], in9[k], ag);
        ab = fmaf(wbp[k], in9[k], ab);
      }
      accG[i] = ag; accB[i] = ab;
    }
  }

  // epilogue: gather avg-path, blend, normalize, write
  const int y = y0 + py, xg = x0 + px;
  int lv[9];
  #pragma unroll
  for (int dy = 0; dy < 3; ++dy)
    #pragma unroll
    for (int dx = 0; dx < 3; ++dx)
      lv[dy * 3 + dx] = labt[(py + 1 + dy) * 20 + (px + 1 + dx)];
  const int cofs = ch * 16;
  float gav[16], bav[16];
  #pragma unroll
  for (int i = 0; i < 16; ++i) { gav[i] = bcgl[cofs + i]; bav[i] = bcbl[cofs + i]; }
  #pragma unroll
  for (int k = 0; k < 9; ++k) {
    const float* row = alut + (lv[k] * 9 + k) * 64;
    #pragma unroll
    for (int i = 0; i < 16; ++i) { gav[i] += row[cofs + i]; bav[i] += row[32 + cofs + i]; }
  }
  const float ga = gab[0], ba = gab[1];
  const float nz = ws[WS_NT + (size_t)(b * 256 + y) * 256 + xg];
  #pragma unroll
  for (int i = 0; i < 16; ++i) {
    int ci = cofs + i, c = c0 + ci;
    float gf = ga * gav[i] + (1.f - ga) * (accG[i] + bgl[ci]);
    float bf = ba * bav[i] + (1.f - ba) * (accB[i] + bbl[ci]);
    size_t off = ((size_t)(b * 128 + c) * 256 + y) * 256 + xg;
    float xn = x[off] + nvl[ci] * nz;
    float nrm = (xn - meanl[ci]) * istdl[ci];
    out[off] = nrm * (1.f + gf) + bf;
  }
}

extern "C" void kernel_launch(void* const* d_in, const int* in_sizes, int n_in,
                              void* d_out, int out_size, void* d_ws, size_t ws_size,
                              hipStream_t stream) {
  const float* x        = (const float*)d_in[0];
  const int*   labels   = (const int*)d_in[1];
  const float* noise    = (const float*)d_in[2];
  const float* style    = (const float*)d_in[3];
  const float* nvar     = (const float*)d_in[4];
  const float* w_sh     = (const float*)d_in[5];
  const float* b_sh     = (const float*)d_in[6];
  const float* w_g      = (const float*)d_in[7];
  const float* b_g      = (const float*)d_in[8];
  const float* w_b      = (const float*)d_in[9];
  const float* b_b      = (const float*)d_in[10];
  const float* Wfc      = (const float*)d_in[11];
  const float* bfc      = (const float*)d_in[12];
  const float* w_cg     = (const float*)d_in[13];
  const float* b_cg     = (const float*)d_in[14];
  const float* w_cb     = (const float*)d_in[15];
  const float* b_cb     = (const float*)d_in[16];
  const float* g_blend  = (const float*)d_in[17];
  const float* b_blend  = (const float*)d_in[18];
  float* ws  = (float*)d_ws;
  float* out = (float*)d_out;

  // allow >64KB dynamic LDS for k_main (no-op if not needed)
  static bool attr_set = false;
  if (!attr_set) {
    (void)hipFuncSetAttribute((const void*)k_main,
                              hipFuncAttributeMaxDynamicSharedMemorySize, 131536);
    attr_set = true;
  }

  hipMemsetAsync((char*)d_ws + (size_t)WS_SUM * 4, 0, 256 * 4, stream);
  hipMemsetAsync((char*)d_ws + (size_t)WS_A2 * 4, 0, (size_t)175104 * 4, stream);

  k_ntrans<<<dim3(8, 8, 4), dim3(32, 8), 0, stream>>>(noise, ws);
  k_stats<<<dim3(512), dim3(256), 0, stream>>>(x, nvar, ws);
  k_finalize<<<dim3(1), dim3(128), 0, stream>>>(ws);
  k_mu<<<dim3(19, 4), dim3(512), 0, stream>>>(style, Wfc, bfc, ws);
  k_atab<<<dim3(8, 4, 4), dim3(288), 0, stream>>>(w_cg, w_cb, ws);
  k_main<<<dim3(16, 16, 16), dim3(512), 131536, stream>>>(
      x, labels, w_sh, b_sh, w_g, b_g, w_b, b_b, b_cg, b_cb,
      nvar, g_blend, b_blend, ws, out);
}

// Round 2
// 542.512 us; speedup vs baseline: 15.7703x; 15.7703x over previous
//
#include <hip/hip_runtime.h>
#include <hip/hip_bf16.h>

#define NB   4
#define FIN  128
#define HH   256
#define WWW  256
#define LLAB 19
#define SSTY 512
#define HW   (HH*WWW)        // 65536
#define NRED (NB*HW)         // 262144

// workspace layout (float offsets)
#define WS_NT   0            // noise transposed [B][H][W]  262144
#define WS_SUM  262144       // 128
#define WS_SSQ  262272       // 128
#define WS_MEAN 262400       // 128
#define WS_ISTD 262528       // 128
#define WS_MU   262656       // 4*19*512 = 38912
#define WS_A2   301568       // 4*19*9*256 = 175104 -> end 476672 floats
// bf16 packed-B regions (byte offsets)
#define WS_BMAIN_B 1906688   // 16 nb * 36 s * 64 lane * 16B = 589824 B
#define WS_BOH_B   2496512   // 4b * 16 nb * 9 kk * 64 lane * 16B = 589824 B
// total ws usage ~3.09 MB

typedef __attribute__((ext_vector_type(8))) short bf16x8;
typedef __attribute__((ext_vector_type(4))) float f32x4;

__device__ inline unsigned short f2bf(float f) {
  __hip_bfloat16 h = __float2bfloat16(f);
  union { __hip_bfloat16 h; unsigned short u; } cv; cv.h = h; return cv.u;
}
__device__ inline float bf2f(short u) {
  union { unsigned int u; float f; } cv;
  cv.u = ((unsigned int)(unsigned short)u) << 16; return cv.f;
}

// ---------------- noise transpose: noise[b][w][h] -> noise_t[b][h][w] --------
__global__ __launch_bounds__(256) void k_ntrans(const float* __restrict__ noise,
                                               float* __restrict__ ws) {
  __shared__ float tile[32][33];
  const int b = blockIdx.z;
  const int w0 = blockIdx.x * 32, h0 = blockIdx.y * 32;
  const int txx = threadIdx.x, tyy = threadIdx.y;
  #pragma unroll
  for (int j = 0; j < 4; ++j) {
    int wi = w0 + tyy + j * 8;
    tile[tyy + j * 8][txx] = noise[(size_t)(b * 256 + wi) * 256 + h0 + txx];
  }
  __syncthreads();
  #pragma unroll
  for (int j = 0; j < 4; ++j) {
    int hi = h0 + tyy + j * 8;
    ws[WS_NT + (size_t)(b * 256 + hi) * 256 + w0 + txx] = tile[txx][tyy + j * 8];
  }
}

// ---------------- per-channel stats over xn = x + nv[c]*noise_t --------------
__global__ __launch_bounds__(256) void k_stats(const float* __restrict__ x,
                                               const float* __restrict__ nv,
                                               float* __restrict__ ws) {
  const int bc = blockIdx.x;
  const int b = bc >> 7, c = bc & 127;
  const int t = threadIdx.x;
  const float4* xp = (const float4*)(x + (size_t)bc * HW);
  const float4* np = (const float4*)(ws + WS_NT + (size_t)b * HW);
  const float nvc = nv[c];
  float s1 = 0.f, s2 = 0.f;
  for (int i = 0; i < 64; ++i) {
    float4 xv = xp[i * 256 + t];
    float4 nz = np[i * 256 + t];
    float v0 = xv.x + nvc * nz.x; s1 += v0; s2 = fmaf(v0, v0, s2);
    float v1 = xv.y + nvc * nz.y; s1 += v1; s2 = fmaf(v1, v1, s2);
    float v2 = xv.z + nvc * nz.z; s1 += v2; s2 = fmaf(v2, v2, s2);
    float v3 = xv.w + nvc * nz.w; s1 += v3; s2 = fmaf(v3, v3, s2);
  }
  #pragma unroll
  for (int m = 32; m; m >>= 1) { s1 += __shfl_xor(s1, m); s2 += __shfl_xor(s2, m); }
  if ((t & 63) == 0) { atomicAdd(&ws[WS_SUM + c], s1); atomicAdd(&ws[WS_SSQ + c], s2); }
}

__global__ __launch_bounds__(128) void k_finalize(float* __restrict__ ws) {
  const int c = threadIdx.x;
  float mean = ws[WS_SUM + c] / (float)NRED;
  float var = ws[WS_SSQ + c] / (float)NRED - mean * mean;
  ws[WS_MEAN + c] = mean;
  ws[WS_ISTD + c] = 1.f / sqrtf(var + 1e-5f);
}

// ---------------- mu[b,j,o] = relu(sum_d style[b,j,d]*Wfc[j,o,d] + bfc[j,o]) -
__global__ __launch_bounds__(512) void k_mu(const float* __restrict__ style,
                                            const float* __restrict__ Wfc,
                                            const float* __restrict__ bfc,
                                            float* __restrict__ ws) {
  const int j = blockIdx.x, b = blockIdx.y, o = threadIdx.x;
  const float4* wrow = (const float4*)(Wfc + ((size_t)j * 512 + o) * 512);
  const float4* srow = (const float4*)(style + ((size_t)b * 19 + j) * 512);
  float acc = 0.f;
  for (int d = 0; d < 128; ++d) {
    float4 w = wrow[d];
    float4 s = srow[d];
    acc = fmaf(w.x, s.x, acc); acc = fmaf(w.y, s.y, acc);
    acc = fmaf(w.z, s.z, acc); acc = fmaf(w.w, s.w, acc);
  }
  acc += bfc[j * 512 + o];
  ws[WS_MU + ((size_t)b * 19 + j) * 512 + o] = fmaxf(acc, 0.f);
}

// ------- A2[b][l][k][conv*128+c] = sum_s mu[b,l,s] * w_conv[c,s,k] -----------
__global__ __launch_bounds__(288) void k_atab(const float* __restrict__ w_cg,
                                              const float* __restrict__ w_cb,
                                              float* __restrict__ ws) {
  __shared__ float wlds[32 * 288];
  const int t = threadIdx.x;
  const int cblk = blockIdx.x, ssplit = blockIdx.y, b = blockIdx.z;
  const int conv = t / 144, r = t % 144, cl = r / 9, k = r % 9;
  const int c = cblk * 16 + cl;
  const float* mu = ws + WS_MU;
  float acc[19];
  #pragma unroll
  for (int l = 0; l < 19; ++l) acc[l] = 0.f;

  for (int chunk = 0; chunk < 4; ++chunk) {
    const int s0 = ssplit * 128 + chunk * 32;
    for (int it = 0; it < 32; ++it) {
      int cv2 = it >> 4, cl2 = it & 15;
      const float* src = cv2 ? w_cb : w_cg;
      float v = src[((size_t)(cblk * 16 + cl2) * 512 + s0) * 9 + t];
      wlds[(t / 9) * 288 + cv2 * 144 + cl2 * 9 + (t % 9)] = v;
    }
    __syncthreads();
    for (int sl = 0; sl < 32; ++sl) {
      float w = wlds[sl * 288 + t];
      int s = s0 + sl;
      #pragma unroll
      for (int l = 0; l < 19; ++l)
        acc[l] = fmaf(mu[((size_t)b * 19 + l) * 512 + s], w, acc[l]);
    }
    __syncthreads();
  }
  #pragma unroll
  for (int l = 0; l < 19; ++l)
    atomicAdd(&ws[WS_A2 + (((size_t)b * 19 + l) * 9 + k) * 256 + conv * 128 + c], acc[l]);
}

// ---- pack main-conv weights: Bpk[nb][s][lane][8] bf16, blend-folded ---------
__global__ __launch_bounds__(256) void k_packmain(const float* __restrict__ w_g,
                                                 const float* __restrict__ w_b,
                                                 const float* __restrict__ g_blend,
                                                 const float* __restrict__ b_blend,
                                                 char* __restrict__ wsb) {
  int tid = blockIdx.x * 256 + threadIdx.x;   // 36864
  int lane = tid & 63, grp = tid >> 6;
  int s = grp % 36, nb = grp / 36;
  int n = nb * 16 + (lane & 15);
  int conv = n & 1, cout = n >> 1;
  float blend = conv ? b_blend[0] : g_blend[0];
  float scale = 1.f - 1.f / (1.f + __expf(-blend));
  const float* src = conv ? w_b : w_g;
  bf16x8 v;
  #pragma unroll
  for (int i = 0; i < 8; ++i) {
    int k = s * 32 + (lane >> 4) * 8 + i;
    int kk = k >> 7, cin = k & 127;
    v[i] = (short)f2bf(scale * src[((size_t)cout * 128 + cin) * 9 + kk]);
  }
  *(bf16x8*)(wsb + WS_BMAIN_B + (size_t)tid * 16) = v;
}

// ---- pack one-hot B: Boh[b][nb][kk][lane][8] bf16 = blend*A2 ----------------
__global__ __launch_bounds__(256) void k_packoh(const float* __restrict__ ws,
                                                const float* __restrict__ g_blend,
                                                const float* __restrict__ b_blend,
                                                char* __restrict__ wsb) {
  int tid = blockIdx.x * 256 + threadIdx.x;   // 36864
  int lane = tid & 63, grp = tid >> 6;
  int kk = grp % 9, nb = (grp / 9) % 16, b = grp / 144;
  int n = nb * 16 + (lane & 15);
  int conv = n & 1, cout = n >> 1;
  float blend = conv ? b_blend[0] : g_blend[0];
  float scale = 1.f / (1.f + __expf(-blend));
  bf16x8 v;
  #pragma unroll
  for (int i = 0; i < 8; ++i) {
    int l = (lane >> 4) * 8 + i;
    float val = 0.f;
    if (l < 19)
      val = scale * ws[WS_A2 + (((size_t)b * 19 + l) * 9 + kk) * 256 + conv * 128 + cout];
    v[i] = (short)f2bf(val);
  }
  *(bf16x8*)(wsb + WS_BOH_B + (size_t)tid * 16) = v;
}

// ---------------- main fused MFMA kernel -------------------------------------
// grid (16,16,4b), block 512 (8 waves: 2 M x 4 N). Tile 16x16 px, N=256.
// LDS: labt 1600 | actv [324][128] bf16 swz 82944 | wsh2 [20][9][128] bf16 46080
//      | small arrays 3072  -> 133696 B
__global__ __launch_bounds__(512, 2) void k_main(
    const float* __restrict__ x, const int* __restrict__ labels,
    const float* __restrict__ w_sh, const float* __restrict__ b_sh,
    const float* __restrict__ b_g, const float* __restrict__ b_b,
    const float* __restrict__ b_cg, const float* __restrict__ b_cb,
    const float* __restrict__ noise_var,
    const float* __restrict__ g_blend, const float* __restrict__ b_blend,
    const float* __restrict__ ws, float* __restrict__ out) {
  extern __shared__ char smem[];
  int* labt = (int*)smem;                    // [20][20]
  char* actv = smem + 1600;                  // [324][128] bf16, XOR-swizzled
  char* wsh2 = smem + 84544;                 // [20][9][128] bf16 (row 0 zeros)
  float* gbias = (float*)(smem + 130624);
  float* bbias = gbias + 128; float* nvl = gbias + 256;
  float* meanl = gbias + 384; float* istdl = gbias + 512; float* bshl = gbias + 640;

  const int t = threadIdx.x;
  const int b = blockIdx.z;
  const int y0 = blockIdx.y * 16, x0 = blockIdx.x * 16;

  // ---- phase 1: small arrays, label tile, w_sh -> LDS ----
  if (t < 128) {
    float ga = 1.f / (1.f + __expf(-g_blend[0]));
    float ba = 1.f / (1.f + __expf(-b_blend[0]));
    gbias[t] = ga * b_cg[t] + (1.f - ga) * b_g[t];
    bbias[t] = ba * b_cb[t] + (1.f - ba) * b_b[t];
    nvl[t] = noise_var[t];
    meanl[t] = ws[WS_MEAN + t];
    istdl[t] = ws[WS_ISTD + t];
    bshl[t] = b_sh[t];
  }
  for (int idx = t; idx < 400; idx += 512) {
    int ly = idx / 20, lx = idx % 20;
    int gy = y0 - 2 + ly, gx = x0 - 2 + lx;
    int v = 0;
    if ((unsigned)gy < 256u && (unsigned)gx < 256u)
      v = labels[((size_t)(b * 256 + gy)) * 256 + gx] + 1;
    labt[idx] = v;
  }
  for (int idx = t; idx < 23040; idx += 512) {   // [l 20][k 9][cin 128]
    int l = idx / 1152, r = idx % 1152, k = r >> 7, cin = r & 127;
    float v = (l == 0) ? 0.f : w_sh[((size_t)cin * 19 + (l - 1)) * 9 + k];
    ((unsigned short*)wsh2)[idx] = f2bf(v);
  }
  __syncthreads();

  // ---- phase 2: actv generation -> LDS [hp 324][cin 128] bf16, swizzled ----
  for (int it = t; it < 5184; it += 512) {       // 324 px * 16 cin-groups
    int hp = it >> 4, cg = it & 15;
    int py = hp / 18, px = hp - py * 18;
    int gy = y0 - 1 + py, gx = x0 - 1 + px;
    int baddr = hp * 256 + ((cg * 16) ^ ((hp & 7) << 4));
    bf16x8 o = {0, 0, 0, 0, 0, 0, 0, 0};
    if ((unsigned)gy < 256u && (unsigned)gx < 256u) {
      float accv[8];
      #pragma unroll
      for (int j = 0; j < 8; ++j) accv[j] = bshl[cg * 8 + j];
      #pragma unroll
      for (int k = 0; k < 9; ++k) {
        int dy = k / 3, dx = k - 3 * (k / 3);
        int lv = labt[(py + dy) * 20 + (px + dx)];
        bf16x8 wvv = *(const bf16x8*)(wsh2 + (size_t)((lv * 9 + k) * 128 + cg * 8) * 2);
        #pragma unroll
        for (int j = 0; j < 8; ++j) accv[j] += bf2f(wvv[j]);
      }
      #pragma unroll
      for (int j = 0; j < 8; ++j) o[j] = (short)f2bf(fmaxf(accv[j], 0.f));
    }
    *(bf16x8*)(actv + baddr) = o;
  }
  __syncthreads();

  // ---- phase 3: K-loop (no barriers). 36 main + 9 one-hot K-steps ----
  const int lane = t & 63;
  const int wid = t >> 6;
  const int wm = wid & 1, wn = wid >> 1;
  const int l15 = lane & 15, l16 = lane >> 4;
  const char* wsb = (const char*)ws;
  const char* bmain = wsb + WS_BMAIN_B;
  const char* boh = wsb + WS_BOH_B;

  f32x4 acc[8][4];
  #pragma unroll
  for (int i = 0; i < 8; ++i)
    #pragma unroll
    for (int j = 0; j < 4; ++j) acc[i][j] = (f32x4){0.f, 0.f, 0.f, 0.f};

  for (int kk = 0; kk < 9; ++kk) {
    const int ky = kk / 3, kx = kk - 3 * (kk / 3);
    #pragma unroll
    for (int cb = 0; cb < 4; ++cb) {
      bf16x8 af[8];
      #pragma unroll
      for (int mf = 0; mf < 8; ++mf) {
        int hp = (wm * 8 + mf + ky) * 18 + l15 + kx;
        int ba = hp * 256 + ((cb * 64 + l16 * 16) ^ ((hp & 7) << 4));
        af[mf] = *(const bf16x8*)(actv + ba);
      }
      bf16x8 bfr[4];
      #pragma unroll
      for (int nf = 0; nf < 4; ++nf) {
        int nb = wn * 4 + nf;
        bfr[nf] = *(const bf16x8*)(bmain + (size_t)(((nb * 36 + kk * 4 + cb) * 64 + lane)) * 16);
      }
      #pragma unroll
      for (int mf = 0; mf < 8; ++mf)
        #pragma unroll
        for (int nf = 0; nf < 4; ++nf)
          acc[mf][nf] = __builtin_amdgcn_mfma_f32_16x16x32_bf16(af[mf], bfr[nf], acc[mf][nf], 0, 0, 0);
    }
    // one-hot K-step for this kk (avg path folded into same accumulators)
    {
      bf16x8 af[8];
      #pragma unroll
      for (int mf = 0; mf < 8; ++mf) {
        int lvv = labt[(wm * 8 + mf + ky + 1) * 20 + l15 + kx + 1] - 1;
        bf16x8 a1;
        #pragma unroll
        for (int i = 0; i < 8; ++i)
          a1[i] = (short)((l16 * 8 + i == lvv) ? 0x3F80 : 0);
        af[mf] = a1;
      }
      bf16x8 bfr[4];
      #pragma unroll
      for (int nf = 0; nf < 4; ++nf) {
        int nb = wn * 4 + nf;
        bfr[nf] = *(const bf16x8*)(boh + (size_t)((((b * 16 + nb) * 9 + kk) * 64 + lane)) * 16);
      }
      #pragma unroll
      for (int mf = 0; mf < 8; ++mf)
        #pragma unroll
        for (int nf = 0; nf < 4; ++nf)
          acc[mf][nf] = __builtin_amdgcn_mfma_f32_16x16x32_bf16(af[mf], bfr[nf], acc[mf][nf], 0, 0, 0);
    }
  }

  // ---- epilogue: pair gamma/beta via shfl_xor(1), normalize, write ----
  const float* nt = ws + WS_NT + (size_t)b * HW;
  #pragma unroll
  for (int mf = 0; mf < 8; ++mf) {
    #pragma unroll
    for (int nf = 0; nf < 4; ++nf) {
      f32x4 v = acc[mf][nf];
      #pragma unroll
      for (int r = 0; r < 4; ++r) {
        float own = v[r];
        float oth = __shfl_xor(own, 1);
        int n = wn * 64 + nf * 16 + l15;
        if (!(n & 1)) {
          int c = n >> 1;
          int p = wm * 128 + mf * 16 + l16 * 4 + r;
          int yy = y0 + (p >> 4), xx = x0 + (p & 15);
          float gf = own + gbias[c];
          float bf_ = oth + bbias[c];
          size_t off = (((size_t)(b * 128 + c)) * 256 + yy) * 256 + xx;
          float xn = x[off] + nvl[c] * nt[yy * 256 + xx];
          float nrm = (xn - meanl[c]) * istdl[c];
          out[off] = nrm * (1.f + gf) + bf_;
        }
      }
    }
  }
}

extern "C" void kernel_launch(void* const* d_in, const int* in_sizes, int n_in,
                              void* d_out, int out_size, void* d_ws, size_t ws_size,
                              hipStream_t stream) {
  const float* x        = (const float*)d_in[0];
  const int*   labels   = (const int*)d_in[1];
  const float* noise    = (const float*)d_in[2];
  const float* style    = (const float*)d_in[3];
  const float* nvar     = (const float*)d_in[4];
  const float* w_sh     = (const float*)d_in[5];
  const float* b_sh     = (const float*)d_in[6];
  const float* w_g      = (const float*)d_in[7];
  const float* b_g      = (const float*)d_in[8];
  const float* w_b      = (const float*)d_in[9];
  const float* b_b      = (const float*)d_in[10];
  const float* Wfc      = (const float*)d_in[11];
  const float* bfc      = (const float*)d_in[12];
  const float* w_cg     = (const float*)d_in[13];
  const float* b_cg     = (const float*)d_in[14];
  const float* w_cb     = (const float*)d_in[15];
  const float* b_cb     = (const float*)d_in[16];
  const float* g_blend  = (const float*)d_in[17];
  const float* b_blend  = (const float*)d_in[18];
  float* ws  = (float*)d_ws;
  char*  wsb = (char*)d_ws;
  float* out = (float*)d_out;

  static bool attr_set = false;
  if (!attr_set) {
    (void)hipFuncSetAttribute((const void*)k_main,
                              hipFuncAttributeMaxDynamicSharedMemorySize, 133760);
    attr_set = true;
  }

  hipMemsetAsync((char*)d_ws + (size_t)WS_SUM * 4, 0, 256 * 4, stream);
  hipMemsetAsync((char*)d_ws + (size_t)WS_A2 * 4, 0, (size_t)175104 * 4, stream);

  k_ntrans<<<dim3(8, 8, 4), dim3(32, 8), 0, stream>>>(noise, ws);
  k_stats<<<dim3(512), dim3(256), 0, stream>>>(x, nvar, ws);
  k_finalize<<<dim3(1), dim3(128), 0, stream>>>(ws);
  k_mu<<<dim3(19, 4), dim3(512), 0, stream>>>(style, Wfc, bfc, ws);
  k_atab<<<dim3(8, 4, 4), dim3(288), 0, stream>>>(w_cg, w_cb, ws);
  k_packmain<<<dim3(144), dim3(256), 0, stream>>>(w_g, w_b, g_blend, b_blend, wsb);
  k_packoh<<<dim3(144), dim3(256), 0, stream>>>(ws, g_blend, b_blend, wsb);
  k_main<<<dim3(16, 16, 4), dim3(512), 133760, stream>>>(
      x, labels, w_sh, b_sh, b_g, b_b, b_cg, b_cb,
      nvar, g_blend, b_blend, ws, out);
}